// Round 8
// baseline (509.991 us; speedup 1.0000x reference)
//
#include <hip/hip_runtime.h>

#define NN 50000
#define NE 800000
#define DD 128
#define RR 8
#define MB (NN * RR)          // 400000 buckets keyed by (r, dst)
#define SCAN_BLK 2048
#define NBLK ((MB + SCAN_BLK - 1) / SCAN_BLK)   // 196

#define HTILES 391            // 64-row tiles per half
#define HROWS (HTILES * 64)   // 25024 rows per half

typedef __attribute__((ext_vector_type(8))) short short8;
typedef __attribute__((ext_vector_type(4))) float f32x4;

__device__ __forceinline__ unsigned short f2bf(float f)
{
    unsigned int u = __float_as_uint(f);
    u = (u + 0x7FFFu + ((u >> 16) & 1u)) >> 16;   // RNE
    return (unsigned short)u;
}
__device__ __forceinline__ float bflo(unsigned int p) { return __uint_as_float(p << 16); }
__device__ __forceinline__ float bfhi(unsigned int p) { return __uint_as_float(p & 0xFFFF0000u); }

// ---------------- count per (relation, dst); atomic return = edge rank ----------------
__global__ __launch_bounds__(256) void k_count(const int* __restrict__ ei,
                                               const int* __restrict__ et,
                                               int* __restrict__ cnt,
                                               unsigned short* __restrict__ rank16)
{
    int e = blockIdx.x * 256 + threadIdx.x;
    if (e < NE) {
        int r = et[e];
        int dst = ei[NE + e];
        int old = atomicAdd(&cnt[r * NN + dst], 1);
        rank16[e] = (unsigned short)old;
    }
}

// ---------------- exclusive scan over cnt -> off ----------------
__global__ __launch_bounds__(256) void k_scan1(const int* __restrict__ cnt,
                                               int* __restrict__ off,
                                               int* __restrict__ bsum)
{
    __shared__ int lds[256];
    int t = threadIdx.x;
    int base = blockIdx.x * SCAN_BLK + t * 8;
    int v[8], s = 0;
    #pragma unroll
    for (int j = 0; j < 8; j++) {
        int idx = base + j;
        v[j] = (idx < MB) ? cnt[idx] : 0;
        s += v[j];
    }
    lds[t] = s;
    __syncthreads();
    for (int d = 1; d < 256; d <<= 1) {
        int u = (t >= d) ? lds[t - d] : 0;
        __syncthreads();
        lds[t] += u;
        __syncthreads();
    }
    if (t == 255) bsum[blockIdx.x] = lds[255];
    int run = lds[t] - s;
    #pragma unroll
    for (int j = 0; j < 8; j++) {
        int idx = base + j;
        if (idx < MB) off[idx] = run;
        run += v[j];
    }
}

__global__ __launch_bounds__(256) void k_scan2(const int* __restrict__ bsum,
                                               int* __restrict__ carry)
{
    __shared__ int lds[256];
    int t = threadIdx.x;
    int s = (t < NBLK) ? bsum[t] : 0;
    lds[t] = s;
    __syncthreads();
    for (int d = 1; d < 256; d <<= 1) {
        int u = (t >= d) ? lds[t - d] : 0;
        __syncthreads();
        lds[t] += u;
        __syncthreads();
    }
    if (t < NBLK) carry[t] = lds[t] - s;
}

__global__ __launch_bounds__(256) void k_scan3(int* __restrict__ off,
                                               const int* __restrict__ carry)
{
    int c = carry[blockIdx.x];
    int base = blockIdx.x * SCAN_BLK + threadIdx.x * 8;
    #pragma unroll
    for (int j = 0; j < 8; j++) {
        int idx = base + j;
        if (idx < MB) off[idx] += c;
    }
    if (blockIdx.x == 0 && threadIdx.x == 0) off[MB] = NE;   // sentinel
}

// ---------------- place edges into CSR slots: NO atomics (rank precomputed) ----------------
__global__ __launch_bounds__(256) void k_place(const int* __restrict__ ei,
                                               const int* __restrict__ et,
                                               const int* __restrict__ off,
                                               const unsigned short* __restrict__ rank16,
                                               unsigned short* __restrict__ srt16)
{
    int e = blockIdx.x * 256 + threadIdx.x;
    if (e < NE) {
        int b = et[e] * NN + ei[NE + e];
        srt16[off[b] + (int)rank16[e]] = (unsigned short)ei[e];   // src < 50000 < 65536
    }
}

// ---------------- f32 -> bf16 convert (vectorized) ----------------
__global__ __launch_bounds__(256) void k_tobf16(const float* __restrict__ x,
                                                unsigned short* __restrict__ xb, int n4)
{
    int i = blockIdx.x * 256 + threadIdx.x;
    if (i < n4) {
        float4 v = ((const float4*)x)[i];
        uint2 o;
        o.x = (unsigned int)f2bf(v.x) | ((unsigned int)f2bf(v.y) << 16);
        o.y = (unsigned int)f2bf(v.z) | ((unsigned int)f2bf(v.w) << 16);
        ((uint2*)xb)[i] = o;
    }
}

// ---------------- weights: transpose + bf16: Wb[m][n][k] = src[m][k][n] ----------------
__global__ __launch_bounds__(256) void k_wconv(const float* __restrict__ W1,
                                               const float* __restrict__ root1,
                                               const float* __restrict__ W2,
                                               const float* __restrict__ root2,
                                               unsigned short* __restrict__ Wb)
{
    int e = blockIdx.x * 256 + threadIdx.x;
    if (e >= 18 * 16384) return;
    int m = e >> 14;
    int rem = e & 16383;
    int n = rem >> 7;
    int k = rem & 127;
    float v;
    if (m < 8)       v = W1[m * 16384 + k * 128 + n];
    else if (m == 8) v = root1[k * 128 + n];
    else if (m < 17) v = W2[(m - 9) * 16384 + k * 128 + n];
    else             v = root2[k * 128 + n];
    Wb[e] = f2bf(v);
}

// ---------------- K-sliced gather + partial GEMM ----------------
// blockIdx b: XCD = b&7 (empirical round-robin), slice = (b>>1)&3 -> XCD pair {2s,2s+1},
// tile = (b>>3)*2 + (b&1) in [0, HTILES). Tile = 64 dst rows; slice = 32 K-cols.
// 512 threads: gather groups = 8 lanes/row (64 rows); MFMA: 8 waves x (16 rows x 64 cols).
// Writes bf16 partial P[slice][lrow][128].
__global__ __launch_bounds__(512) void k_gather(const unsigned short* __restrict__ Xin,
                                                const unsigned short* __restrict__ Wb,
                                                const int* __restrict__ off,
                                                const unsigned short* __restrict__ srt16,
                                                unsigned short* __restrict__ P,
                                                int row0)
{
    __shared__ unsigned short Wl[128 * 40];   // [n][k] slice, 80B row stride (pad)
    __shared__ unsigned short Al[64 * 40];    // [row][k] slice, 80B row stride
    const int t = threadIdx.x;
    const int b = blockIdx.x;
    const int slice = (b >> 1) & 3;
    const int tile = (b >> 3) * 2 + (b & 1);
    if (tile >= HTILES) return;
    const int ks0 = slice * 32;
    const int grow0 = row0 + tile * 64;
    const int g8 = t >> 3, l8 = t & 7;        // gather: row group / col-quad
    const int lane = t & 63, w = t >> 6;
    const int rt = w >> 1, ch = w & 1;        // MFMA: row-tile / col-half
    const int cl = lane & 15, kq = lane >> 4;

    // ---- phase 1: gather all 8 relations for row grow0+g8, slice cols ----
    float a[8][4];
    int cdeg[8];
    #pragma unroll
    for (int m = 0; m < 8; m++) {
        a[m][0] = a[m][1] = a[m][2] = a[m][3] = 0.f;
        cdeg[m] = 0;
    }
    float ar0 = 0.f, ar1 = 0.f, ar2 = 0.f, ar3 = 0.f;
    int row = grow0 + g8;
    if (row < NN) {
        int s_[8], e_[8];
        #pragma unroll
        for (int m = 0; m < 8; m++) s_[m] = off[m * NN + row];
        #pragma unroll
        for (int m = 0; m < 8; m++) e_[m] = off[m * NN + row + 1];
        #pragma unroll
        for (int m = 0; m < 8; m++) {
            int s = s_[m];
            int c = e_[m] - s;
            cdeg[m] = c;
            int k = 0;
            for (; k + 2 <= c; k += 2) {
                int p0 = (int)srt16[s + k];
                int p1 = (int)srt16[s + k + 1];
                uint2 u0 = *(const uint2*)(Xin + (size_t)p0 * 128 + ks0 + l8 * 4);
                uint2 u1 = *(const uint2*)(Xin + (size_t)p1 * 128 + ks0 + l8 * 4);
                a[m][0] += bflo(u0.x) + bflo(u1.x); a[m][1] += bfhi(u0.x) + bfhi(u1.x);
                a[m][2] += bflo(u0.y) + bflo(u1.y); a[m][3] += bfhi(u0.y) + bfhi(u1.y);
            }
            if (k < c) {
                int p0 = (int)srt16[s + k];
                uint2 u0 = *(const uint2*)(Xin + (size_t)p0 * 128 + ks0 + l8 * 4);
                a[m][0] += bflo(u0.x); a[m][1] += bfhi(u0.x);
                a[m][2] += bflo(u0.y); a[m][3] += bfhi(u0.y);
            }
        }
        uint2 ur = *(const uint2*)(Xin + (size_t)row * 128 + ks0 + l8 * 4);
        ar0 = bflo(ur.x); ar1 = bfhi(ur.x); ar2 = bflo(ur.y); ar3 = bfhi(ur.y);
    }

    f32x4 acc[4];
    #pragma unroll
    for (int ct = 0; ct < 4; ct++) acc[ct] = f32x4{0.f, 0.f, 0.f, 0.f};

    // ---- phase 2: per matrix m (8 relations + root), K=32 MFMA step ----
    for (int m = 0; m < 9; m++) {
        // pack A_m slice (scaled) into Al
        {
            float v0, v1, v2, v3;
            if (m < 8) {
                float invc = 1.0f / (float)(cdeg[m] > 1 ? cdeg[m] : 1);
                v0 = a[m][0] * invc; v1 = a[m][1] * invc;
                v2 = a[m][2] * invc; v3 = a[m][3] * invc;
            } else {
                v0 = ar0; v1 = ar1; v2 = ar2; v3 = ar3;
            }
            uint2 o;
            o.x = (unsigned int)f2bf(v0) | ((unsigned int)f2bf(v1) << 16);
            o.y = (unsigned int)f2bf(v2) | ((unsigned int)f2bf(v3) << 16);
            *(uint2*)((char*)Al + g8 * 80 + l8 * 8) = o;
        }
        // stage W_m slice [128 n][32 k] into Wl
        {
            int n = t >> 2, q = t & 3;
            uint4 v = *(const uint4*)(Wb + (size_t)m * 16384 + n * 128 + ks0 + q * 8);
            *(uint4*)((char*)Wl + n * 80 + q * 16) = v;
        }
        __syncthreads();
        // one K=32 MFMA step, 4 col-tiles per wave
        {
            short8 af = *(const short8*)((const char*)Al + (rt * 16 + cl) * 80 + kq * 16);
            #pragma unroll
            for (int ct = 0; ct < 4; ct++) {
                int n = ch * 64 + ct * 16 + cl;
                short8 bfr = *(const short8*)((const char*)Wl + n * 80 + kq * 16);
                acc[ct] = __builtin_amdgcn_mfma_f32_16x16x32_bf16(af, bfr, acc[ct], 0, 0, 0);
            }
        }
        __syncthreads();
    }

    // ---- store bf16 partial ----
    #pragma unroll
    for (int ct = 0; ct < 4; ct++) {
        int col = ch * 64 + ct * 16 + cl;
        #pragma unroll
        for (int j = 0; j < 4; j++) {
            int lr = tile * 64 + rt * 16 + kq * 4 + j;
            P[((size_t)slice * HROWS + lr) * 128 + col] = f2bf(acc[ct][j]);
        }
    }
}

// ---------------- reduce 4 slice-partials + bias; relu->bf16 | L2-norm->f32 ----------------
__global__ __launch_bounds__(256) void k_reduce(const unsigned short* __restrict__ P,
                                                const float* __restrict__ bias,
                                                unsigned short* __restrict__ out_bf,
                                                float* __restrict__ out_f,
                                                int row0, int mode)
{
    int lr = blockIdx.x * 4 + (threadIdx.x >> 6);
    int row = row0 + lr;
    if (lr >= HROWS || row >= NN) return;
    int lane = threadIdx.x & 63;
    int col = lane * 2;
    float sx = 0.f, sy = 0.f;
    #pragma unroll
    for (int s = 0; s < 4; s++) {
        unsigned int u = *(const unsigned int*)(P + ((size_t)s * HROWS + lr) * 128 + col);
        sx += bflo(u); sy += bfhi(u);
    }
    float2 bb = *(const float2*)(bias + col);
    sx += bb.x; sy += bb.y;
    if (mode == 0) {
        sx = fmaxf(sx, 0.f); sy = fmaxf(sy, 0.f);
        unsigned int o = (unsigned int)f2bf(sx) | ((unsigned int)f2bf(sy) << 16);
        *(unsigned int*)(out_bf + (size_t)row * 128 + col) = o;
    } else {
        float ss = sx * sx + sy * sy;
        #pragma unroll
        for (int o = 32; o > 0; o >>= 1) ss += __shfl_xor(ss, o);
        float inv = 1.0f / fmaxf(sqrtf(ss), 1e-12f);
        float2 o2; o2.x = sx * inv; o2.y = sy * inv;
        *(float2*)(out_f + (size_t)row * 128 + col) = o2;
    }
}

extern "C" void kernel_launch(void* const* d_in, const int* in_sizes, int n_in,
                              void* d_out, int out_size, void* d_ws, size_t ws_size,
                              hipStream_t stream)
{
    const float* x     = (const float*)d_in[0];
    const int*   ei    = (const int*)d_in[1];   // [2, E]
    const int*   et    = (const int*)d_in[2];   // [E]
    const float* W1    = (const float*)d_in[3];
    const float* root1 = (const float*)d_in[4];
    const float* b1    = (const float*)d_in[5];
    const float* W2    = (const float*)d_in[6];
    const float* root2 = (const float*)d_in[7];
    const float* b2    = (const float*)d_in[8];
    float* out = (float*)d_out;

    char* ws = (char*)d_ws;
    int* cnt   = (int*)ws;                                  // MB ints      (1.6 MB)
    int* off   = cnt + MB;                                  // MB+1 ints    (1.6 MB)
    int* bsum  = off + MB + 1;                              // 256
    int* carry = bsum + 256;                                // 256
    unsigned short* rank16 = (unsigned short*)(carry + 256);        // NE u16 (1.6 MB)
    unsigned short* srt16  = rank16 + NE;                           // NE u16 (1.6 MB)
    unsigned short* Xb     = srt16 + NE;                            // NN*128 (12.8 MB)
    unsigned short* hb     = Xb + (size_t)NN * DD;                  // NN*128 (12.8 MB)
    unsigned short* Wb     = hb + (size_t)NN * DD;                  // 18*16384 (0.58 MB)
    unsigned short* P      = Wb + (size_t)18 * 16384;               // 4*HROWS*128 (25.6 MB)

    hipMemsetAsync(cnt, 0, (size_t)MB * 4, stream);

    k_count<<<(NE + 255) / 256, 256, 0, stream>>>(ei, et, cnt, rank16);
    k_scan1<<<NBLK, 256, 0, stream>>>(cnt, off, bsum);
    k_scan2<<<1, 256, 0, stream>>>(bsum, carry);
    k_scan3<<<NBLK, 256, 0, stream>>>(off, carry);
    k_place<<<(NE + 255) / 256, 256, 0, stream>>>(ei, et, off, rank16, srt16);

    k_tobf16<<<(NN * DD / 4 + 255) / 256, 256, 0, stream>>>(x, Xb, NN * DD / 4);
    k_wconv<<<(18 * 16384 + 255) / 256, 256, 0, stream>>>(W1, root1, W2, root2, Wb);

    const int g_grid = 1568;                 // 196 q-steps x 8 (4 slices x 2 tile-lanes)
    const int r_grid = (HROWS + 3) / 4;      // 6256

    // ---- layer 1: hb = relu(x@root1 + b1 + sum_r mean_r(x)@W1r) ----
    for (int h = 0; h < 2; h++) {
        k_gather<<<g_grid, 512, 0, stream>>>(Xb, Wb, off, srt16, P, h * HROWS);
        k_reduce<<<r_grid, 256, 0, stream>>>(P, b1, hb, nullptr, h * HROWS, 0);
    }
    // ---- layer 2: out = normalize(hb@root2 + b2 + sum_r mean_r(hb)@W2r) ----
    for (int h = 0; h < 2; h++) {
        k_gather<<<g_grid, 512, 0, stream>>>(hb, Wb + (size_t)9 * 16384, off, srt16, P, h * HROWS);
        k_reduce<<<r_grid, 256, 0, stream>>>(P, b2, nullptr, out, h * HROWS, 1);
    }
}

// Round 10
// 407.288 us; speedup vs baseline: 1.2522x; 1.2522x over previous
//
#include <hip/hip_runtime.h>

#define NN 50000
#define NE 800000
#define DD 128
#define RR 8
#define MB (NN * RR)          // 400000 buckets keyed by (dst, r)
#define SCAN_BLK 2048
#define NBLK ((MB + SCAN_BLK - 1) / SCAN_BLK)   // 196

typedef __attribute__((ext_vector_type(8))) short short8;
typedef __attribute__((ext_vector_type(4))) float f32x4;

__device__ __forceinline__ unsigned short f2bf(float f)
{
    unsigned int u = __float_as_uint(f);
    u = (u + 0x7FFFu + ((u >> 16) & 1u)) >> 16;   // RNE
    return (unsigned short)u;
}
__device__ __forceinline__ float bflo(unsigned int p) { return __uint_as_float(p << 16); }
__device__ __forceinline__ float bfhi(unsigned int p) { return __uint_as_float(p & 0xFFFF0000u); }

// ---------------- count per (dst, relation); atomic return = edge rank ----------------
__global__ __launch_bounds__(256) void k_count(const int* __restrict__ ei,
                                               const int* __restrict__ et,
                                               int* __restrict__ cnt,
                                               unsigned short* __restrict__ rank16)
{
    int e = blockIdx.x * 256 + threadIdx.x;
    if (e < NE) {
        int r = et[e];
        int dst = ei[NE + e];
        int old = atomicAdd(&cnt[dst * RR + r], 1);
        rank16[e] = (unsigned short)old;
    }
}

// ---------------- exclusive scan over cnt -> off ----------------
__global__ __launch_bounds__(256) void k_scan1(const int* __restrict__ cnt,
                                               int* __restrict__ off,
                                               int* __restrict__ bsum)
{
    __shared__ int lds[256];
    int t = threadIdx.x;
    int base = blockIdx.x * SCAN_BLK + t * 8;
    int v[8], s = 0;
    #pragma unroll
    for (int j = 0; j < 8; j++) {
        int idx = base + j;
        v[j] = (idx < MB) ? cnt[idx] : 0;
        s += v[j];
    }
    lds[t] = s;
    __syncthreads();
    for (int d = 1; d < 256; d <<= 1) {
        int u = (t >= d) ? lds[t - d] : 0;
        __syncthreads();
        lds[t] += u;
        __syncthreads();
    }
    if (t == 255) bsum[blockIdx.x] = lds[255];
    int run = lds[t] - s;
    #pragma unroll
    for (int j = 0; j < 8; j++) {
        int idx = base + j;
        if (idx < MB) off[idx] = run;
        run += v[j];
    }
}

__global__ __launch_bounds__(256) void k_scan2(const int* __restrict__ bsum,
                                               int* __restrict__ carry)
{
    __shared__ int lds[256];
    int t = threadIdx.x;
    int s = (t < NBLK) ? bsum[t] : 0;
    lds[t] = s;
    __syncthreads();
    for (int d = 1; d < 256; d <<= 1) {
        int u = (t >= d) ? lds[t - d] : 0;
        __syncthreads();
        lds[t] += u;
        __syncthreads();
    }
    if (t < NBLK) carry[t] = lds[t] - s;
}

__global__ __launch_bounds__(256) void k_scan3(int* __restrict__ off,
                                               const int* __restrict__ carry)
{
    int c = carry[blockIdx.x];
    int base = blockIdx.x * SCAN_BLK + threadIdx.x * 8;
    #pragma unroll
    for (int j = 0; j < 8; j++) {
        int idx = base + j;
        if (idx < MB) off[idx] += c;
    }
    if (blockIdx.x == 0 && threadIdx.x == 0) off[MB] = NE;   // sentinel
}

// ---------------- place edges into CSR slots: NO atomics (rank precomputed) ----------------
__global__ __launch_bounds__(256) void k_place(const int* __restrict__ ei,
                                               const int* __restrict__ et,
                                               const int* __restrict__ off,
                                               const unsigned short* __restrict__ rank16,
                                               unsigned short* __restrict__ srt16)
{
    int e = blockIdx.x * 256 + threadIdx.x;
    if (e < NE) {
        int b = ei[NE + e] * RR + et[e];
        srt16[off[b] + (int)rank16[e]] = (unsigned short)ei[e];   // src < 50000 < 65536
    }
}

// ---------------- f32 -> bf16 convert (vectorized) ----------------
__global__ __launch_bounds__(256) void k_tobf16(const float* __restrict__ x,
                                                unsigned short* __restrict__ xb, int n4)
{
    int i = blockIdx.x * 256 + threadIdx.x;
    if (i < n4) {
        float4 v = ((const float4*)x)[i];
        uint2 o;
        o.x = (unsigned int)f2bf(v.x) | ((unsigned int)f2bf(v.y) << 16);
        o.y = (unsigned int)f2bf(v.z) | ((unsigned int)f2bf(v.w) << 16);
        ((uint2*)xb)[i] = o;
    }
}

// ---------------- weights: transpose + bf16: Wb[m][n][k] = src[m][k][n] ----------------
__global__ __launch_bounds__(256) void k_wconv(const float* __restrict__ W1,
                                               const float* __restrict__ root1,
                                               const float* __restrict__ W2,
                                               const float* __restrict__ root2,
                                               unsigned short* __restrict__ Wb)
{
    int e = blockIdx.x * 256 + threadIdx.x;
    if (e >= 18 * 16384) return;
    int m = e >> 14;
    int rem = e & 16383;
    int n = rem >> 7;
    int k = rem & 127;
    float v;
    if (m < 8)       v = W1[m * 16384 + k * 128 + n];
    else if (m == 8) v = root1[k * 128 + n];
    else if (m < 17) v = W2[(m - 9) * 16384 + k * 128 + n];
    else             v = root2[k * 128 + n];
    Wb[e] = f2bf(v);
}

// ---------------- fused layer: high-MLP gather, ONE barrier, W direct from L2 ----------------
// 16 dst-rows x 128 cols per block (grid 3125 exact), 512 threads (8 waves).
// Gather: 32 lanes/row (lane covers 4 cols via uint2), predicated 4-deep per relation.
// MFMA: wave w = col-tile, 16x16 output, A from 32KB swizzled Al (plane stride 4096 B).
__global__ __launch_bounds__(512, 6) void k_layer(const unsigned short* __restrict__ Xin,
                                                  const unsigned short* __restrict__ Wb,
                                                  const float* __restrict__ bias,
                                                  const int* __restrict__ off,
                                                  const unsigned short* __restrict__ srt16,
                                                  unsigned short* __restrict__ out_bf,
                                                  float* __restrict__ out_f,
                                                  int mode)
{
    __shared__ unsigned short Al[8 * 16 * 128];   // 32 KB: plane m = [16 rows][128 k], XOR swizzled
    __shared__ float nrm[16 * 8];                 // row-norm partials per col-tile
    const int t = threadIdx.x;
    const int w = t >> 6;            // wave = col-tile ct
    const int lane = t & 63;
    const int grow0 = blockIdx.x * 16;
    const int cl = lane & 15;
    const int kq = lane >> 4;
    const int g = t >> 5;            // local row 0..15
    const int l32 = t & 31;          // lane-in-row: cols 4*l32 .. 4*l32+3

    // ---- phase 1: gather all 8 relations for row = grow0 + g ----
    float a[8][4];
    int cd[8];
    #pragma unroll
    for (int m = 0; m < 8; m++) {
        a[m][0] = a[m][1] = a[m][2] = a[m][3] = 0.f;
    }
    const int row = grow0 + g;       // always < NN (grid exact)
    const int ob = row * 8;
    int o0 = off[ob],     o1 = off[ob + 1], o2 = off[ob + 2];
    int o3 = off[ob + 3], o4 = off[ob + 4], o5 = off[ob + 5];
    int o6 = off[ob + 6], o7 = off[ob + 7], o8 = off[ob + 8];

#define REL(MM, SS, EE)                                                          \
    {                                                                            \
        int s = (SS); int c = (EE) - (SS); cd[MM] = c;                           \
        int i0 = 0, i1 = 0, i2 = 0, i3 = 0;                                      \
        if (c > 0) i0 = srt16[s];                                                \
        if (c > 1) i1 = srt16[s + 1];                                            \
        if (c > 2) i2 = srt16[s + 2];                                            \
        if (c > 3) i3 = srt16[s + 3];                                            \
        uint2 u0 = {0,0}, u1 = {0,0}, u2 = {0,0}, u3 = {0,0};                    \
        if (c > 0) u0 = *(const uint2*)(Xin + (size_t)i0 * 128 + l32 * 4);       \
        if (c > 1) u1 = *(const uint2*)(Xin + (size_t)i1 * 128 + l32 * 4);       \
        if (c > 2) u2 = *(const uint2*)(Xin + (size_t)i2 * 128 + l32 * 4);       \
        if (c > 3) u3 = *(const uint2*)(Xin + (size_t)i3 * 128 + l32 * 4);       \
        a[MM][0] += bflo(u0.x) + bflo(u1.x) + bflo(u2.x) + bflo(u3.x);           \
        a[MM][1] += bfhi(u0.x) + bfhi(u1.x) + bfhi(u2.x) + bfhi(u3.x);           \
        a[MM][2] += bflo(u0.y) + bflo(u1.y) + bflo(u2.y) + bflo(u3.y);           \
        a[MM][3] += bfhi(u0.y) + bfhi(u1.y) + bfhi(u2.y) + bfhi(u3.y);           \
        for (int k = 4; k < c; k++) {                                            \
            int ii = srt16[s + k];                                               \
            uint2 uu = *(const uint2*)(Xin + (size_t)ii * 128 + l32 * 4);        \
            a[MM][0] += bflo(uu.x); a[MM][1] += bfhi(uu.x);                      \
            a[MM][2] += bflo(uu.y); a[MM][3] += bfhi(uu.y);                      \
        }                                                                        \
    }

    REL(0, o0, o1) REL(1, o1, o2) REL(2, o2, o3) REL(3, o3, o4)
    REL(4, o4, o5) REL(5, o5, o6) REL(6, o6, o7) REL(7, o7, o8)
#undef REL

    // dump scaled means into Al (one uint2 per relation per lane); plane stride 4096 B
    #pragma unroll
    for (int m = 0; m < 8; m++) {
        float invc = 1.0f / (float)(cd[m] > 1 ? cd[m] : 1);
        uint2 ov;
        ov.x = (unsigned int)f2bf(a[m][0] * invc) | ((unsigned int)f2bf(a[m][1] * invc) << 16);
        ov.y = (unsigned int)f2bf(a[m][2] * invc) | ((unsigned int)f2bf(a[m][3] * invc) << 16);
        int byteoff = m * 4096 + ((g * 256 + l32 * 8) ^ ((g & 7) << 4));
        *(uint2*)((char*)Al + byteoff) = ov;
    }
    __syncthreads();

    // ---- phase 2: 9 matrices x 4 K-steps, B fragments direct from global (L2-hot) ----
    f32x4 acc = f32x4{0.f, 0.f, 0.f, 0.f};
    const int n = w * 16 + cl;       // output col this lane accumulates
    #pragma unroll
    for (int m = 0; m < 8; m++) {
        #pragma unroll
        for (int ks = 0; ks < 4; ks++) {
            int abyte = m * 4096 + ((cl * 256 + ks * 64 + kq * 16) ^ ((cl & 7) << 4));
            short8 af = *(const short8*)((const char*)Al + abyte);
            short8 bfr = *(const short8*)(Wb + (size_t)m * 16384 + n * 128 + ks * 32 + kq * 8);
            acc = __builtin_amdgcn_mfma_f32_16x16x32_bf16(af, bfr, acc, 0, 0, 0);
        }
    }
    {   // root term: A straight from global Xin
        int rg = grow0 + cl;
        #pragma unroll
        for (int ks = 0; ks < 4; ks++) {
            short8 af = *(const short8*)(Xin + (size_t)rg * 128 + ks * 32 + kq * 8);
            short8 bfr = *(const short8*)(Wb + (size_t)8 * 16384 + n * 128 + ks * 32 + kq * 8);
            acc = __builtin_amdgcn_mfma_f32_16x16x32_bf16(af, bfr, acc, 0, 0, 0);
        }
    }

    // ---- epilogue ----
    float bc = bias[n];
    if (mode == 0) {
        #pragma unroll
        for (int j = 0; j < 4; j++) {
            int rw = grow0 + kq * 4 + j;
            float v = fmaxf(acc[j] + bc, 0.f);
            out_bf[(size_t)rw * 128 + n] = f2bf(v);
        }
    } else {
        float vv[4], ss[4];
        #pragma unroll
        for (int j = 0; j < 4; j++) {
            float v = acc[j] + bc;
            vv[j] = v;
            ss[j] = v * v;
        }
        #pragma unroll
        for (int j = 0; j < 4; j++) {
            #pragma unroll
            for (int o = 1; o < 16; o <<= 1) ss[j] += __shfl_xor(ss[j], o);
        }
        if (cl == 0) {
            #pragma unroll
            for (int j = 0; j < 4; j++) nrm[(kq * 4 + j) * 8 + w] = ss[j];
        }
        __syncthreads();
        #pragma unroll
        for (int j = 0; j < 4; j++) {
            int rl = kq * 4 + j;
            float tot = 0.f;
            #pragma unroll
            for (int c = 0; c < 8; c++) tot += nrm[rl * 8 + c];
            float inv = 1.0f / fmaxf(sqrtf(tot), 1e-12f);
            out_f[(size_t)(grow0 + rl) * 128 + n] = vv[j] * inv;
        }
    }
}

extern "C" void kernel_launch(void* const* d_in, const int* in_sizes, int n_in,
                              void* d_out, int out_size, void* d_ws, size_t ws_size,
                              hipStream_t stream)
{
    const float* x     = (const float*)d_in[0];
    const int*   ei    = (const int*)d_in[1];   // [2, E]
    const int*   et    = (const int*)d_in[2];   // [E]
    const float* W1    = (const float*)d_in[3];
    const float* root1 = (const float*)d_in[4];
    const float* b1    = (const float*)d_in[5];
    const float* W2    = (const float*)d_in[6];
    const float* root2 = (const float*)d_in[7];
    const float* b2    = (const float*)d_in[8];
    float* out = (float*)d_out;

    char* ws = (char*)d_ws;
    int* cnt   = (int*)ws;                                  // MB ints
    int* off   = cnt + MB;                                  // MB+1 ints
    int* bsum  = off + MB + 1;                              // 256
    int* carry = bsum + 256;                                // 256
    unsigned short* rank16 = (unsigned short*)(carry + 256);        // NE u16
    unsigned short* srt16  = rank16 + NE;                           // NE u16
    unsigned short* Xb     = srt16 + NE;                            // NN*128 bf16
    unsigned short* hb     = Xb + (size_t)NN * DD;                  // NN*128 bf16
    unsigned short* Wb     = hb + (size_t)NN * DD;                  // 18*16384 bf16

    hipMemsetAsync(cnt, 0, (size_t)MB * 4, stream);

    k_count<<<(NE + 255) / 256, 256, 0, stream>>>(ei, et, cnt, rank16);
    k_scan1<<<NBLK, 256, 0, stream>>>(cnt, off, bsum);
    k_scan2<<<1, 256, 0, stream>>>(bsum, carry);
    k_scan3<<<NBLK, 256, 0, stream>>>(off, carry);
    k_place<<<(NE + 255) / 256, 256, 0, stream>>>(ei, et, off, rank16, srt16);

    k_tobf16<<<(NN * DD / 4 + 255) / 256, 256, 0, stream>>>(x, Xb, NN * DD / 4);
    k_wconv<<<(18 * 16384 + 255) / 256, 256, 0, stream>>>(W1, root1, W2, root2, Wb);

    const int lay_grid = NN / 16;   // 3125, exact
    // layer 1: hb = relu(x@root1 + b1 + sum_r mean_r(x)@W1r)
    k_layer<<<lay_grid, 512, 0, stream>>>(Xb, Wb, b1, off, srt16, hb, nullptr, 0);
    // layer 2: out = normalize(hb@root2 + b2 + sum_r mean_r(hb)@W2r)
    k_layer<<<lay_grid, 512, 0, stream>>>(hb, Wb + (size_t)9 * 16384, b2, off, srt16, nullptr, out, 1);
}

// Round 11
// 406.350 us; speedup vs baseline: 1.2551x; 1.0023x over previous
//
#include <hip/hip_runtime.h>

#define NN 50000
#define NE 800000
#define DD 128
#define RR 8
#define MB (NN * RR)          // 400000 buckets keyed by (dst, r)
#define SCAN_BLK 2048
#define NBLK ((MB + SCAN_BLK - 1) / SCAN_BLK)   // 196

typedef __attribute__((ext_vector_type(8))) short short8;
typedef __attribute__((ext_vector_type(4))) float f32x4;

__device__ __forceinline__ unsigned short f2bf(float f)
{
    unsigned int u = __float_as_uint(f);
    u = (u + 0x7FFFu + ((u >> 16) & 1u)) >> 16;   // RNE
    return (unsigned short)u;
}
__device__ __forceinline__ float bflo(unsigned int p) { return __uint_as_float(p << 16); }
__device__ __forceinline__ float bfhi(unsigned int p) { return __uint_as_float(p & 0xFFFF0000u); }

// ---------------- count per (dst, relation); atomic return = edge rank ----------------
__global__ __launch_bounds__(256) void k_count(const int* __restrict__ ei,
                                               const int* __restrict__ et,
                                               int* __restrict__ cnt,
                                               unsigned short* __restrict__ rank16)
{
    int e = blockIdx.x * 256 + threadIdx.x;
    if (e < NE) {
        int r = et[e];
        int dst = ei[NE + e];
        int old = atomicAdd(&cnt[dst * RR + r], 1);
        rank16[e] = (unsigned short)old;
    }
}

// ---------------- exclusive scan over cnt -> off ----------------
__global__ __launch_bounds__(256) void k_scan1(const int* __restrict__ cnt,
                                               int* __restrict__ off,
                                               int* __restrict__ bsum)
{
    __shared__ int lds[256];
    int t = threadIdx.x;
    int base = blockIdx.x * SCAN_BLK + t * 8;
    int v[8], s = 0;
    #pragma unroll
    for (int j = 0; j < 8; j++) {
        int idx = base + j;
        v[j] = (idx < MB) ? cnt[idx] : 0;
        s += v[j];
    }
    lds[t] = s;
    __syncthreads();
    for (int d = 1; d < 256; d <<= 1) {
        int u = (t >= d) ? lds[t - d] : 0;
        __syncthreads();
        lds[t] += u;
        __syncthreads();
    }
    if (t == 255) bsum[blockIdx.x] = lds[255];
    int run = lds[t] - s;
    #pragma unroll
    for (int j = 0; j < 8; j++) {
        int idx = base + j;
        if (idx < MB) off[idx] = run;
        run += v[j];
    }
}

__global__ __launch_bounds__(256) void k_scan2(const int* __restrict__ bsum,
                                               int* __restrict__ carry)
{
    __shared__ int lds[256];
    int t = threadIdx.x;
    int s = (t < NBLK) ? bsum[t] : 0;
    lds[t] = s;
    __syncthreads();
    for (int d = 1; d < 256; d <<= 1) {
        int u = (t >= d) ? lds[t - d] : 0;
        __syncthreads();
        lds[t] += u;
        __syncthreads();
    }
    if (t < NBLK) carry[t] = lds[t] - s;
}

__global__ __launch_bounds__(256) void k_scan3(int* __restrict__ off,
                                               const int* __restrict__ carry)
{
    int c = carry[blockIdx.x];
    int base = blockIdx.x * SCAN_BLK + threadIdx.x * 8;
    #pragma unroll
    for (int j = 0; j < 8; j++) {
        int idx = base + j;
        if (idx < MB) off[idx] += c;
    }
    if (blockIdx.x == 0 && threadIdx.x == 0) off[MB] = NE;   // sentinel
}

// ---------------- place edges into CSR slots: NO atomics (rank precomputed) ----------------
__global__ __launch_bounds__(256) void k_place(const int* __restrict__ ei,
                                               const int* __restrict__ et,
                                               const int* __restrict__ off,
                                               const unsigned short* __restrict__ rank16,
                                               unsigned short* __restrict__ srt16)
{
    int e = blockIdx.x * 256 + threadIdx.x;
    if (e < NE) {
        int b = ei[NE + e] * RR + et[e];
        srt16[off[b] + (int)rank16[e]] = (unsigned short)ei[e];   // src < 50000 < 65536
    }
}

// ---------------- f32 -> bf16 convert (vectorized) ----------------
__global__ __launch_bounds__(256) void k_tobf16(const float* __restrict__ x,
                                                unsigned short* __restrict__ xb, int n4)
{
    int i = blockIdx.x * 256 + threadIdx.x;
    if (i < n4) {
        float4 v = ((const float4*)x)[i];
        uint2 o;
        o.x = (unsigned int)f2bf(v.x) | ((unsigned int)f2bf(v.y) << 16);
        o.y = (unsigned int)f2bf(v.z) | ((unsigned int)f2bf(v.w) << 16);
        ((uint2*)xb)[i] = o;
    }
}

// ---------------- weights: transpose + bf16: Wb[m][n][k] = src[m][k][n] ----------------
__global__ __launch_bounds__(256) void k_wconv(const float* __restrict__ W1,
                                               const float* __restrict__ root1,
                                               const float* __restrict__ W2,
                                               const float* __restrict__ root2,
                                               unsigned short* __restrict__ Wb)
{
    int e = blockIdx.x * 256 + threadIdx.x;
    if (e >= 18 * 16384) return;
    int m = e >> 14;
    int rem = e & 16383;
    int n = rem >> 7;
    int k = rem & 127;
    float v;
    if (m < 8)       v = W1[m * 16384 + k * 128 + n];
    else if (m == 8) v = root1[k * 128 + n];
    else if (m < 17) v = W2[(m - 9) * 16384 + k * 128 + n];
    else             v = root2[k * 128 + n];
    Wb[e] = f2bf(v);
}

// ---------------- fused layer: high-MLP gather, ONE barrier, W direct from L2 ----------------
// 16 dst-rows x 128 cols per block (grid 3125 exact), 512 threads (8 waves).
// Gather: 32 lanes/row (lane covers 4 cols via uint2), predicated 4-deep per relation;
// each relation's mean is packed to bf16 immediately (short accumulator live range).
// MFMA: wave w = col-tile, 16x16 output, A from 32KB swizzled Al (plane stride 4096 B).
__global__ __launch_bounds__(512, 2) void k_layer(const unsigned short* __restrict__ Xin,
                                                  const unsigned short* __restrict__ Wb,
                                                  const float* __restrict__ bias,
                                                  const int* __restrict__ off,
                                                  const unsigned short* __restrict__ srt16,
                                                  unsigned short* __restrict__ out_bf,
                                                  float* __restrict__ out_f,
                                                  int mode)
{
    __shared__ unsigned short Al[8 * 16 * 128];   // 32 KB: plane m = [16 rows][128 k], XOR swizzled
    __shared__ float nrm[16 * 8];                 // row-norm partials per col-tile
    const int t = threadIdx.x;
    const int w = t >> 6;            // wave = col-tile ct
    const int lane = t & 63;
    const int grow0 = blockIdx.x * 16;
    const int cl = lane & 15;
    const int kq = lane >> 4;
    const int g = t >> 5;            // local row 0..15
    const int l32 = t & 31;          // lane-in-row: cols 4*l32 .. 4*l32+3

    // ---- phase 1: gather all 8 relations for row = grow0 + g ----
    const int row = grow0 + g;       // always < NN (grid exact)
    const int ob = row * 8;
    int o0 = off[ob],     o1 = off[ob + 1], o2 = off[ob + 2];
    int o3 = off[ob + 3], o4 = off[ob + 4], o5 = off[ob + 5];
    int o6 = off[ob + 6], o7 = off[ob + 7], o8 = off[ob + 8];

    uint2 pk[8];   // packed bf16 means, 2 regs each (static unrolled indexing)

#define REL(MM, SS, EE)                                                          \
    {                                                                            \
        int s = (SS); int c = (EE) - (SS);                                       \
        int i0 = 0, i1 = 0, i2 = 0, i3 = 0;                                      \
        if (c > 0) i0 = srt16[s];                                                \
        if (c > 1) i1 = srt16[s + 1];                                            \
        if (c > 2) i2 = srt16[s + 2];                                            \
        if (c > 3) i3 = srt16[s + 3];                                            \
        uint2 u0 = {0,0}, u1 = {0,0}, u2 = {0,0}, u3 = {0,0};                    \
        if (c > 0) u0 = *(const uint2*)(Xin + (size_t)i0 * 128 + l32 * 4);       \
        if (c > 1) u1 = *(const uint2*)(Xin + (size_t)i1 * 128 + l32 * 4);       \
        if (c > 2) u2 = *(const uint2*)(Xin + (size_t)i2 * 128 + l32 * 4);       \
        if (c > 3) u3 = *(const uint2*)(Xin + (size_t)i3 * 128 + l32 * 4);       \
        float a0 = bflo(u0.x) + bflo(u1.x) + bflo(u2.x) + bflo(u3.x);            \
        float a1 = bfhi(u0.x) + bfhi(u1.x) + bfhi(u2.x) + bfhi(u3.x);            \
        float a2 = bflo(u0.y) + bflo(u1.y) + bflo(u2.y) + bflo(u3.y);            \
        float a3 = bfhi(u0.y) + bfhi(u1.y) + bfhi(u2.y) + bfhi(u3.y);            \
        for (int k = 4; k < c; k++) {                                            \
            int ii = srt16[s + k];                                               \
            uint2 uu = *(const uint2*)(Xin + (size_t)ii * 128 + l32 * 4);        \
            a0 += bflo(uu.x); a1 += bfhi(uu.x);                                  \
            a2 += bflo(uu.y); a3 += bfhi(uu.y);                                  \
        }                                                                        \
        float invc = 1.0f / (float)(c > 1 ? c : 1);                              \
        pk[MM].x = (unsigned int)f2bf(a0 * invc) | ((unsigned int)f2bf(a1 * invc) << 16); \
        pk[MM].y = (unsigned int)f2bf(a2 * invc) | ((unsigned int)f2bf(a3 * invc) << 16); \
    }

    REL(0, o0, o1) REL(1, o1, o2) REL(2, o2, o3) REL(3, o3, o4)
    REL(4, o4, o5) REL(5, o5, o6) REL(6, o6, o7) REL(7, o7, o8)
#undef REL

    // dump packed means into Al; plane stride 4096 B
    #pragma unroll
    for (int m = 0; m < 8; m++) {
        int byteoff = m * 4096 + ((g * 256 + l32 * 8) ^ ((g & 7) << 4));
        *(uint2*)((char*)Al + byteoff) = pk[m];
    }
    __syncthreads();

    // ---- phase 2: 9 matrices x 4 K-steps, B fragments direct from global (L2-hot) ----
    f32x4 acc = f32x4{0.f, 0.f, 0.f, 0.f};
    const int n = w * 16 + cl;       // output col this lane accumulates
    #pragma unroll
    for (int m = 0; m < 8; m++) {
        #pragma unroll
        for (int ks = 0; ks < 4; ks++) {
            int abyte = m * 4096 + ((cl * 256 + ks * 64 + kq * 16) ^ ((cl & 7) << 4));
            short8 af = *(const short8*)((const char*)Al + abyte);
            short8 bfr = *(const short8*)(Wb + (size_t)m * 16384 + n * 128 + ks * 32 + kq * 8);
            acc = __builtin_amdgcn_mfma_f32_16x16x32_bf16(af, bfr, acc, 0, 0, 0);
        }
    }
    {   // root term: A straight from global Xin
        int rg = grow0 + cl;
        #pragma unroll
        for (int ks = 0; ks < 4; ks++) {
            short8 af = *(const short8*)(Xin + (size_t)rg * 128 + ks * 32 + kq * 8);
            short8 bfr = *(const short8*)(Wb + (size_t)8 * 16384 + n * 128 + ks * 32 + kq * 8);
            acc = __builtin_amdgcn_mfma_f32_16x16x32_bf16(af, bfr, acc, 0, 0, 0);
        }
    }

    // ---- epilogue ----
    float bc = bias[n];
    if (mode == 0) {
        #pragma unroll
        for (int j = 0; j < 4; j++) {
            int rw = grow0 + kq * 4 + j;
            float v = fmaxf(acc[j] + bc, 0.f);
            out_bf[(size_t)rw * 128 + n] = f2bf(v);
        }
    } else {
        float vv[4], ss[4];
        #pragma unroll
        for (int j = 0; j < 4; j++) {
            float v = acc[j] + bc;
            vv[j] = v;
            ss[j] = v * v;
        }
        #pragma unroll
        for (int j = 0; j < 4; j++) {
            #pragma unroll
            for (int o = 1; o < 16; o <<= 1) ss[j] += __shfl_xor(ss[j], o);
        }
        if (cl == 0) {
            #pragma unroll
            for (int j = 0; j < 4; j++) nrm[(kq * 4 + j) * 8 + w] = ss[j];
        }
        __syncthreads();
        #pragma unroll
        for (int j = 0; j < 4; j++) {
            int rl = kq * 4 + j;
            float tot = 0.f;
            #pragma unroll
            for (int c = 0; c < 8; c++) tot += nrm[rl * 8 + c];
            float inv = 1.0f / fmaxf(sqrtf(tot), 1e-12f);
            out_f[(size_t)(grow0 + rl) * 128 + n] = vv[j] * inv;
        }
    }
}

extern "C" void kernel_launch(void* const* d_in, const int* in_sizes, int n_in,
                              void* d_out, int out_size, void* d_ws, size_t ws_size,
                              hipStream_t stream)
{
    const float* x     = (const float*)d_in[0];
    const int*   ei    = (const int*)d_in[1];   // [2, E]
    const int*   et    = (const int*)d_in[2];   // [E]
    const float* W1    = (const float*)d_in[3];
    const float* root1 = (const float*)d_in[4];
    const float* b1    = (const float*)d_in[5];
    const float* W2    = (const float*)d_in[6];
    const float* root2 = (const float*)d_in[7];
    const float* b2    = (const float*)d_in[8];
    float* out = (float*)d_out;

    char* ws = (char*)d_ws;
    int* cnt   = (int*)ws;                                  // MB ints
    int* off   = cnt + MB;                                  // MB+1 ints
    int* bsum  = off + MB + 1;                              // 256
    int* carry = bsum + 256;                                // 256
    unsigned short* rank16 = (unsigned short*)(carry + 256);        // NE u16
    unsigned short* srt16  = rank16 + NE;                           // NE u16
    unsigned short* Xb     = srt16 + NE;                            // NN*128 bf16
    unsigned short* hb     = Xb + (size_t)NN * DD;                  // NN*128 bf16
    unsigned short* Wb     = hb + (size_t)NN * DD;                  // 18*16384 bf16

    hipMemsetAsync(cnt, 0, (size_t)MB * 4, stream);

    k_count<<<(NE + 255) / 256, 256, 0, stream>>>(ei, et, cnt, rank16);
    k_scan1<<<NBLK, 256, 0, stream>>>(cnt, off, bsum);
    k_scan2<<<1, 256, 0, stream>>>(bsum, carry);
    k_scan3<<<NBLK, 256, 0, stream>>>(off, carry);
    k_place<<<(NE + 255) / 256, 256, 0, stream>>>(ei, et, off, rank16, srt16);

    k_tobf16<<<(NN * DD / 4 + 255) / 256, 256, 0, stream>>>(x, Xb, NN * DD / 4);
    k_wconv<<<(18 * 16384 + 255) / 256, 256, 0, stream>>>(W1, root1, W2, root2, Wb);

    const int lay_grid = NN / 16;   // 3125, exact
    // layer 1: hb = relu(x@root1 + b1 + sum_r mean_r(x)@W1r)
    k_layer<<<lay_grid, 512, 0, stream>>>(Xb, Wb, b1, off, srt16, hb, nullptr, 0);
    // layer 2: out = normalize(hb@root2 + b2 + sum_r mean_r(hb)@W2r)
    k_layer<<<lay_grid, 512, 0, stream>>>(hb, Wb + (size_t)9 * 16384, b2, off, srt16, nullptr, out, 1);
}